// Round 11
// baseline (368.804 us; speedup 1.0000x reference)
//
#include <hip/hip_runtime.h>
#include <hip/hip_bf16.h>
#include <math.h>

// ---------------------------------------------------------------------------
// RPN fused kernel for MI355X (gfx950)
//   trunk : 3x3 conv 64->512 + bias + relu   (fp16 MFMA, 32x32x16)
//   heads : 1x1 conv 512->9 (sigmoid) and 512->36 (linear), deltas masked by
//           score > 0.7, output [B,H,W,45] fp32
// Round 14: trunk MFMA shape 16x16x32 -> 32x32x16 on the R12 base (best=282us).
//   R13 refuted the L2-BW theory (halved traffic, no gain) and confirmed
//   R12's 3-waves/SIMD config. Remaining lever: per-MFMA efficiency --
//   32x32x16 = 1014 FLOP/SIMD-cyc vs 844 (m119/m06), -17% MFMA pipe time,
//   and halves trunk instruction count (144 vs 288). Same acc reg count
//   (4x f32x16 = 64), same B traffic shape.
//   Layouts: A/B in: row|col=lane&31, k=(lane>>5)*8+e (16x16 pattern
//   generalized); C/D: col=lane&31, row=(r&3)+8*(r>>2)+4*(lane>>5) [m74/m101].
//   Head / reduction / epilogue byte-identical to R12; dump remapped.
//   Trunk FP accumulation order changes (K=16 HW chunks) -> absmax may move
//   off the 0.00390625 canary; weight-quant error still dominates (~0.004).
// ---------------------------------------------------------------------------

typedef _Float16 fp16x8 __attribute__((ext_vector_type(8)));
typedef _Float16 fp16x4 __attribute__((ext_vector_type(4)));
typedef float    f32x4  __attribute__((ext_vector_type(4)));
typedef float    f32x16 __attribute__((ext_vector_type(16)));

#define BT_ELEMS  (18 * 32 * 64 * 8)    // 294912 trunk weights fp16
#define BT2_ELEMS (48 * 512)            // head weights, [o][k] k-major
#define BS_BYTES  32768                 // trunk weight bytes per s-step

// ---------------------------------------------------------------------------
// prep: trunk weights -> fp16 bt32[s][wave][h][j][lane][8] (frag l = h*4+j
//       at l*1024 B within the wave's 8 KB s-step block -- same addressing
//       as before, new internal meaning for 32x32 frags);
//       head weights hi/lo (unchanged).
// ---------------------------------------------------------------------------
__global__ __launch_bounds__(256) void rpn_prep(
    const float* __restrict__ wb,   // [3][3][64][512]
    const float* __restrict__ wc,   // [512][9]
    const float* __restrict__ wr,   // [512][36]
    _Float16* __restrict__ btI,
    _Float16* __restrict__ bt2_hi, _Float16* __restrict__ bt2_lo)
{
    int t = blockIdx.x * 256 + threadIdx.x;
    if (t < BT_ELEMS) {
        int e    = t & 7;
        int lane = (t >> 3) & 63;
        int j    = (t >> 9) & 3;         // N-tile (32 ch) within wave slice
        int h    = (t >> 11) & 1;        // k-half (16) within s-step
        int wv   = (t >> 12) & 3;
        int s    = t >> 14;              // 0..17
        int n    = wv * 128 + j * 32 + (lane & 31);
        int k    = s * 32 + h * 16 + ((lane >> 5) << 3) + e;   // 0..575
        int tap  = k >> 6, c = k & 63;   // k = (ky*3+kx)*64 + c
        btI[t] = (_Float16)wb[(tap * 64 + c) * 512 + n];
    } else if (t < BT_ELEMS + BT2_ELEMS) {
        int jj = t - BT_ELEMS;
        int k = jj & 511;
        int o = jj >> 9;                 // 0..47
        float v = 0.f;
        if (o < 9)       v = wc[k * 9 + o];
        else if (o < 45) v = wr[k * 36 + (o - 9)];
        _Float16 h = (_Float16)v;
        bt2_hi[jj] = h;
        bt2_lo[jj] = (_Float16)(v - (float)h);
    }
}

// ---------------------------------------------------------------------------
// main fused kernel: 8192 workgroups x 256 threads (R12 config)
//   tile = 32 output positions (2 h-rows x 16 w) x 512 channels
//   wave w owns channel slice [128w, 128w+128); acc32[4] = 64 AGPR
// LDS arena (29376 B):
//   xs_hi [4][18][76] fp16 @ 0                     (10944 B; trunk, shared)
//   fbuf per wave @ 10944 + w*4608                 (18432 B; head, wave-private)
//   zb [4][32][50] f32 @ 0 overlay                 (25600 B; after barrier 3)
//   NO barrier between trunk and head (fbuf disjoint from xs, head wave-local).
// ---------------------------------------------------------------------------
#define XS_STRIDE   76
#define FB_OFF      10944
#define FB_PER_WAVE 4608
#define ZB_SLICE    1600                 // floats per wave slice (32*50)
#define ARENA_BYTES 29376

// A-frag ds_read pair (k-halves h=0,1) for s-step S into AH[2]
//   position m = lane&31 -> h-row hp=(lane>>4)&1, w' = lane&15
//   k-local   = (S&1)*32 + h*16 + (lane>>5)*8 + e
#define LOAD_AH(S, AH)                                                        \
    {                                                                         \
        const int tap_ = (S) >> 1;                                            \
        const int ky_  = tap_ / 3;                                            \
        const int kx_  = tap_ - ky_ * 3;                                      \
        _Pragma("unroll")                                                     \
        for (int h = 0; h < 2; ++h)                                           \
            AH[h] = *(const fp16x8*)&xs_hi[((hp + ky_) * 18 + lr + kx_) * XS_STRIDE \
                                           + ((S) & 1) * 32 + h * 16 + l5 * 8]; \
    }

// 8 MFMAs (2 k-halves x 4 N-tiles) from registers
#define MFMA_STEP(AH, BREG)                                                   \
    {                                                                         \
        __builtin_amdgcn_s_setprio(1);                                        \
        _Pragma("unroll")                                                     \
        for (int j = 0; j < 4; ++j)                                           \
            acc32[j] = __builtin_amdgcn_mfma_f32_32x32x16_f16(AH[0], BREG[j], acc32[j], 0, 0, 0); \
        _Pragma("unroll")                                                     \
        for (int j = 0; j < 4; ++j)                                           \
            acc32[j] = __builtin_amdgcn_mfma_f32_32x32x16_f16(AH[1], BREG[4 + j], acc32[j], 0, 0, 0); \
        __builtin_amdgcn_s_setprio(0);                                        \
    }

__global__ __launch_bounds__(256, 3) void rpn_main(
    const float* __restrict__ x,        // [4][256][256][64]
    const float* __restrict__ b_base,   // [512]
    const float* __restrict__ b_cls,    // [9]
    const float* __restrict__ b_reg,    // [36]
    const _Float16* __restrict__ btI,
    const _Float16* __restrict__ bt2_hi, const _Float16* __restrict__ bt2_lo,
    float* __restrict__ out)            // [4][256][256][45]
{
    __shared__ char smem[ARENA_BYTES];
    _Float16* xs_hi = (_Float16*)smem;          // trunk phase only
    float*    zb    = (float*)smem;             // reduction phase only

    const int tid  = threadIdx.x;
    const int wave = tid >> 6;
    const int lane = tid & 63;
    const int q    = lane >> 4;         // 0..3   (head 16x16 indexing)
    const int lr   = lane & 15;         // 0..15
    const int l5   = lane >> 5;         // 0..1   (trunk 32x32 k-group)
    const int hp   = (lane >> 4) & 1;   // 0..1   (trunk position h-row)
    const int l31  = lane & 31;         // 0..31  (trunk position w / channel col)
    const int n0   = wave * 128;        // wave's channel-slice base

    const int wg  = blockIdx.x;
    const int b   = wg >> 11;           // 2048 tiles per image
    const int rem = wg & 2047;
    const int h0  = (rem >> 4) * 2;     // 2 h-rows per tile
    const int w0  = (rem & 15) * 16;    // 16 w-positions per tile

    // ---- stage x patch FIRST (HBM, longest latency): 4 rows x 18 pos x 64 ch ----
    for (int i = 0; i < 5; ++i) {
        int flat = tid + i * 256;
        if (flat < 4 * 18 * 16) {
            int cq  = flat & 15;          // channel quad
            int rp  = flat >> 4;          // 0..71
            int row = rp / 18;
            int pos = rp - row * 18;
            int hh  = h0 - 1 + row;
            int ww  = w0 - 1 + pos;
            fp16x4 h4;
            if (hh >= 0 && hh < 256 && ww >= 0 && ww < 256) {
                const float4 v = *(const float4*)&x[(((b * 256 + hh) * 256 + ww) * 64 + cq * 4)];
                h4[0] = (_Float16)v.x; h4[1] = (_Float16)v.y;
                h4[2] = (_Float16)v.z; h4[3] = (_Float16)v.w;
            } else {
                #pragma unroll
                for (int jz = 0; jz < 4; ++jz) h4[jz] = (_Float16)0.f;
            }
            *(fp16x4*)&xs_hi[(row * 18 + pos) * XS_STRIDE + cq * 4] = h4;
        }
    }

    // wave's B-frag base in global: frag (s,wave,l=h*4+j,lane) at
    //   s*32768 + wave*8192 + l*1024 + lane*16 bytes
    const char* gW = (const char*)btI + wave * 8192 + lane * 16;

    // ---- issue B(s=0) into registers (L2; latency hides under barrier 1) ----
    fp16x8 bA[8], bB[8];
    #pragma unroll
    for (int l = 0; l < 8; ++l)
        bA[l] = *(const fp16x8*)(gW + (size_t)l * 1024);

    __syncthreads();   // barrier 1: xs ready (all waves read all of it)

    // ---- trunk K-loop: 18 s-steps, barrier-free, reg-double-buffered B AND A ----
    f32x16 acc32[4];
    #pragma unroll
    for (int j = 0; j < 4; ++j)
        #pragma unroll
        for (int r = 0; r < 16; ++r)
            acc32[j][r] = 0.f;

    fp16x8 ahA[2], ahB[2];
    LOAD_AH(0, ahA);

    #pragma unroll
    for (int s = 0; s < 18; s += 2) {
        {   // prefetch B(s+1) -> bB (always exists: s+1 <= 17)
            const char* g1 = gW + (size_t)(s + 1) * BS_BYTES;
            #pragma unroll
            for (int l = 0; l < 8; ++l)
                bB[l] = *(const fp16x8*)(g1 + (size_t)l * 1024);
        }
        LOAD_AH(s + 1, ahB);         // A(s+1) reads overlap MFMA(s)
        MFMA_STEP(ahA, bA);
        if (s + 2 < 18) {            // prefetch B(s+2) -> bA, A(s+2) -> ahA
            const char* g2 = gW + (size_t)(s + 2) * BS_BYTES;
            #pragma unroll
            for (int l = 0; l < 8; ++l)
                bA[l] = *(const fp16x8*)(g2 + (size_t)l * 1024);
            LOAD_AH(s + 2, ahA);
        }
        MFMA_STEP(ahB, bB);
    }

    // NO barrier here: fbuf region is disjoint from xs and wave-private.

    // ---- fused 1x1 heads: per-wave k-slice GEMM feat[32][128] x w2[128][48] ----
    _Float16* fh = (_Float16*)(smem + FB_OFF + wave * FB_PER_WAVE);
    _Float16* fl = fh + 32 * 36;

    f32x4 acc2[2][3];
    #pragma unroll
    for (int km = 0; km < 2; ++km)
        #pragma unroll
        for (int ns = 0; ns < 3; ++ns)
            acc2[km][ns] = (f32x4){0.f, 0.f, 0.f, 0.f};

    // preload sub-0 head weights (L2)
    fp16x8 cwh0, cwl0, cwh1, cwh2;
    {
        const int kg0 = n0 + q * 8;
        cwh0 = *(const fp16x8*)&bt2_hi[(0 * 16 + lr) * 512 + kg0];
        cwl0 = *(const fp16x8*)&bt2_lo[(0 * 16 + lr) * 512 + kg0];
        cwh1 = *(const fp16x8*)&bt2_hi[(1 * 16 + lr) * 512 + kg0];
        cwh2 = *(const fp16x8*)&bt2_hi[(2 * 16 + lr) * 512 + kg0];
    }

    #pragma unroll
    for (int sub = 0; sub < 4; ++sub) {       // k-chunk of 32 == N-tile j
        // dump this wave's 32-channel slice of feat (bias+relu, fp16 hi/lo)
        // acc32[sub] layout: channel col = lane&31, row m = (r&3)+8*(r>>2)+4*l5
        {
            float bias = b_base[n0 + sub * 32 + l31];
            #pragma unroll
            for (int r = 0; r < 16; ++r) {
                float v = acc32[sub][r] + bias;
                v = v > 0.f ? v : 0.f;
                _Float16 hh = (_Float16)v;
                int m = (r & 3) + 8 * (r >> 2) + 4 * l5;
                fh[m * 36 + l31] = hh;
                fl[m * 36 + l31] = (_Float16)(v - (float)hh);
            }
        }

        // prefetch NEXT sub's head weights (used ~600 cyc later)
        fp16x8 nwh0, nwl0, nwh1, nwh2;
        if (sub < 3) {
            const int kgn = n0 + (sub + 1) * 32 + q * 8;
            nwh0 = *(const fp16x8*)&bt2_hi[(0 * 16 + lr) * 512 + kgn];
            nwl0 = *(const fp16x8*)&bt2_lo[(0 * 16 + lr) * 512 + kgn];
            nwh1 = *(const fp16x8*)&bt2_hi[(1 * 16 + lr) * 512 + kgn];
            nwh2 = *(const fp16x8*)&bt2_hi[(2 * 16 + lr) * 512 + kgn];
        }

        asm volatile("s_waitcnt lgkmcnt(0)" ::: "memory");  // wave-local RAW fence

        // A-frags: feat rows, k-local = q*8..q*8+7 (8-byte aligned -> 2x b64)
        fp16x8 fah[2], fal[2];
        #pragma unroll
        for (int km = 0; km < 2; ++km) {
            int off = (km * 16 + lr) * 36 + q * 8;
            union { fp16x8 v8; fp16x4 v4[2]; } uh, ul;
            uh.v4[0] = *(const fp16x4*)&fh[off];
            uh.v4[1] = *(const fp16x4*)&fh[off + 4];
            ul.v4[0] = *(const fp16x4*)&fl[off];
            ul.v4[1] = *(const fp16x4*)&fl[off + 4];
            fah[km] = uh.v8;
            fal[km] = ul.v8;
        }

        __builtin_amdgcn_s_setprio(1);
        // ns = 0 (contains the 9 score cols): 3-pass hi/lo
        #pragma unroll
        for (int km = 0; km < 2; ++km)
            acc2[km][0] = __builtin_amdgcn_mfma_f32_16x16x32_f16(fah[km], cwh0, acc2[km][0], 0, 0, 0);
        #pragma unroll
        for (int km = 0; km < 2; ++km)
            acc2[km][0] = __builtin_amdgcn_mfma_f32_16x16x32_f16(fah[km], cwl0, acc2[km][0], 0, 0, 0);
        #pragma unroll
        for (int km = 0; km < 2; ++km)
            acc2[km][0] = __builtin_amdgcn_mfma_f32_16x16x32_f16(fal[km], cwh0, acc2[km][0], 0, 0, 0);
        // ns = 1,2 (pure delta cols): 2-pass (w fp16 single, feat hi+lo)
        #pragma unroll
        for (int km = 0; km < 2; ++km)
            acc2[km][1] = __builtin_amdgcn_mfma_f32_16x16x32_f16(fah[km], cwh1, acc2[km][1], 0, 0, 0);
        #pragma unroll
        for (int km = 0; km < 2; ++km)
            acc2[km][1] = __builtin_amdgcn_mfma_f32_16x16x32_f16(fal[km], cwh1, acc2[km][1], 0, 0, 0);
        #pragma unroll
        for (int km = 0; km < 2; ++km)
            acc2[km][2] = __builtin_amdgcn_mfma_f32_16x16x32_f16(fah[km], cwh2, acc2[km][2], 0, 0, 0);
        #pragma unroll
        for (int km = 0; km < 2; ++km)
            acc2[km][2] = __builtin_amdgcn_mfma_f32_16x16x32_f16(fal[km], cwh2, acc2[km][2], 0, 0, 0);
        __builtin_amdgcn_s_setprio(0);

        if (sub < 3) { cwh0 = nwh0; cwl0 = nwl0; cwh1 = nwh1; cwh2 = nwh2; }
    }

    __syncthreads();   // barrier 3: all xs reads AND fbuf reads done; zb overlay safe

    // ---- parallel cross-wave partials: wave w -> zb slice w [32][50] ----
    {
        float* zw = zb + wave * ZB_SLICE;
        #pragma unroll
        for (int km = 0; km < 2; ++km)
            #pragma unroll
            for (int ns = 0; ns < 3; ++ns)
                #pragma unroll
                for (int r = 0; r < 4; ++r) {
                    int row = km * 16 + q * 4 + r;
                    int col = ns * 16 + lr;
                    zw[row * 50 + col] = acc2[km][ns][r];
                }
    }
    __syncthreads();   // barrier 4: partials visible

    // ---- epilogue: sum k-slices (fixed order), sigmoid, mask, store ----
    for (int i = tid; i < 32 * 45; i += 256) {
        int m = i / 45;
        int o = i - m * 45;
        int e0 = m * 50 + o;
        float z = ((zb[e0] + zb[ZB_SLICE + e0]) + zb[2 * ZB_SLICE + e0]) + zb[3 * ZB_SLICE + e0];
        float v;
        if (o < 9) {
            v = 1.f / (1.f + expf(-(z + b_cls[o])));
        } else {
            int d = o - 9;
            int a = d >> 2;
            int ea = m * 50 + a;
            float za = ((zb[ea] + zb[ZB_SLICE + ea]) + zb[2 * ZB_SLICE + ea]) + zb[3 * ZB_SLICE + ea];
            float s = 1.f / (1.f + expf(-(za + b_cls[a])));
            v = (s > 0.7f) ? (z + b_reg[d]) : 0.f;
        }
        int mh = m >> 4, mw = m & 15;
        out[(((b * 256 + h0 + mh) * 256) + w0 + mw) * 45 + o] = v;
    }
}

// ---------------------------------------------------------------------------
extern "C" void kernel_launch(void* const* d_in, const int* in_sizes, int n_in,
                              void* d_out, int out_size, void* d_ws, size_t ws_size,
                              hipStream_t stream)
{
    const float* x      = (const float*)d_in[0];
    const float* w_base = (const float*)d_in[1];
    const float* b_base = (const float*)d_in[2];
    const float* w_cls  = (const float*)d_in[3];
    const float* b_cls  = (const float*)d_in[4];
    const float* w_reg  = (const float*)d_in[5];
    const float* b_reg  = (const float*)d_in[6];
    float* out = (float*)d_out;

    _Float16* btI    = (_Float16*)d_ws;
    _Float16* bt2_hi = btI + BT_ELEMS;
    _Float16* bt2_lo = bt2_hi + BT2_ELEMS;

    rpn_prep<<<(BT_ELEMS + BT2_ELEMS + 255) / 256, 256, 0, stream>>>(
        w_base, w_cls, w_reg, btI, bt2_hi, bt2_lo);
    rpn_main<<<8192, 256, 0, stream>>>(
        x, b_base, b_cls, b_reg, btI, bt2_hi, bt2_lo, out);
}